// Round 7
// baseline (178277.063 us; speedup 1.0000x reference)
//
#include <hip/hip_runtime.h>
#include <math.h>

#define Bn 256
#define Tn 128
#define En 768
#define HEn 256
#define Hn 512
#define SLOTn 120
#define INTENTn 64
#define EMBn 40
#define NEGV -1e12f
#define NBLK 256
#define NTHR 512

__device__ __forceinline__ float sigm(float x) { return 1.0f / (1.0f + expf(-x)); }

__device__ __forceinline__ float4 f4zero() { float4 z; z.x = z.y = z.z = z.w = 0.f; return z; }

// ---------------------------------------------------------------------------
__global__ void prezero_k(unsigned* __restrict__ p) {
    if (threadIdx.x < 8) p[threadIdx.x] = 0u;
}

// ---------------------------------------------------------------------------
// Manual grid barrier. Safe: grid (256 blocks x 512thr, <=43.5KB LDS, <=128 VGPR
// via launch_bounds) is fully co-resident (>=2 blocks/CU capacity on >=128 CUs).
// Agent-scope atomics + threadfence give cross-XCD visibility (G16).
__device__ __forceinline__ void gsync(unsigned* bar, unsigned* gen) {
    __syncthreads();
    if (threadIdx.x == 0) {
        __threadfence();
        unsigned g = __hip_atomic_load(gen, __ATOMIC_RELAXED, __HIP_MEMORY_SCOPE_AGENT);
        unsigned a = __hip_atomic_fetch_add(bar, 1u, __ATOMIC_ACQ_REL, __HIP_MEMORY_SCOPE_AGENT) + 1u;
        if (a == (unsigned)NBLK) {
            __hip_atomic_store(bar, 0u, __ATOMIC_RELAXED, __HIP_MEMORY_SCOPE_AGENT);
            __hip_atomic_store(gen, g + 1u, __ATOMIC_RELEASE, __HIP_MEMORY_SCOPE_AGENT);
        } else {
            while (__hip_atomic_load(gen, __ATOMIC_ACQUIRE, __HIP_MEMORY_SCOPE_AGENT) == g)
                __builtin_amdgcn_s_sleep(8);
        }
        __threadfence();
    }
    __syncthreads();
}

// ---------------------------------------------------------------------------
struct SmemGemm { float Bs[2][64][68]; float Gs[32][68]; };            // 43520 B
struct SmemEn   { float As[2][32][68]; float Bs2[2][32][68]; };        // 34816 B
struct SmemAttn { float hs[512]; float red2[8][132]; float es[128];
                  float pacc2[2][128]; float sc[128]; float ctxp[4][512];
                  float logZ; int amax; };                             // ~16.5 KB
struct SmemInt  { float pacc[8][64]; };                                // 2 KB

__device__ __forceinline__ float4 enc_wload(const float* __restrict__ Wih,
                                            const float* __restrict__ Whh,
                                            int jrow, int k) {
    return (k < En) ? *(const float4*)(Wih + (size_t)jrow * En + k)
                    : *(const float4*)(Whh + (size_t)jrow * HEn + (k - En));
}

__device__ __forceinline__ float4 dec_wload(const float* __restrict__ Wih,
                                            const float* __restrict__ Whh,
                                            int jrow, int k) {
    if (k < 1064) return *(const float4*)(Wih + (size_t)jrow * 1064 + k);
    if (k < 1576) return *(const float4*)(Whh + ((size_t)jrow << 9) + (k - 1064));
    return f4zero();
}

// ---------------------------------------------------------------------------
extern "C" __global__ __launch_bounds__(NTHR, 4) void mega_k(
    const float* __restrict__ seq, const int* __restrict__ nwp,
    const unsigned char* __restrict__ mask_u8, const int* __restrict__ mask_i32,
    const float* __restrict__ embt,
    const float* __restrict__ Wf_ih, const float* __restrict__ Wf_hh,
    const float* __restrict__ bf_ih, const float* __restrict__ bf_hh,
    const float* __restrict__ Wb_ih, const float* __restrict__ Wb_hh,
    const float* __restrict__ bb_ih, const float* __restrict__ bb_hh,
    const float* __restrict__ Wd_ih, const float* __restrict__ Wd_hh,
    const float* __restrict__ bd_ih, const float* __restrict__ bd_hh,
    const float* __restrict__ attn_W, const float* __restrict__ slot_W,
    const float* __restrict__ slot_b,
    const float* __restrict__ intent_W, const float* __restrict__ intent_b,
    float* __restrict__ enc, float* __restrict__ energT,
    float* hf0, float* hf1, float* cf, float* hb0, float* hb1, float* cb,
    float* hd0, float* hd1, float* cd,
    float* ctx0b, float* ctx1b, float* h0s, float* ctx0s, float* embb,
    float* wT4, float* zbase, int nzero,
    unsigned* bar, unsigned* gen, int* mflag,
    float* out_slot, float* out_intent)
{
    __shared__ __align__(16) char smraw[sizeof(SmemGemm)];
    const int bid = blockIdx.x;
    const int tid = threadIdx.x;

    // ================= Phase 0: init =================
    for (int i = bid * NTHR + tid; i < nzero; i += NBLK * NTHR) zbase[i] = 0.f;
    {   // slot_W transpose: exactly 131072 = NBLK*NTHR elements
        int idx = bid * NTHR + tid;
        int k = idx >> 7, s = idx & 127;
        float v = (s < SLOTn) ? slot_W[(size_t)s * 1024 + k] : 0.f;
        wT4[((size_t)(k >> 2) * 128 + s) * 4 + (k & 3)] = v;
    }
    if (bid == 0) {  // mask dtype detect (u8 vs int32); mflag prezeroed
        int found = 0;
        for (int i = tid; i < 32768; i += NTHR)
            if ((i & 3) != 0 && mask_u8[i] != 0) found = 1;
        if (found) atomicOr(mflag, 1);
    }
    gsync(bar, gen);

    // ================= Phase 1: encoder (128 steps) =================
    {
        const int dir = bid >> 7;
        const int jb  = bid & 15;
        const int b0  = ((bid >> 4) & 7) << 5;
        const float* __restrict__ Wih = dir ? Wb_ih : Wf_ih;
        const float* __restrict__ Whh = dir ? Wb_hh : Wf_hh;
        const float* __restrict__ bih = dir ? bb_ih : bf_ih;
        const float* __restrict__ bhh = dir ? bb_hh : bf_hh;
        float* __restrict__ c_st = dir ? cb : cf;
        SmemGemm* sg = (SmemGemm*)smraw;

        const int c   = tid & 63;
        const int wid = tid >> 6;
        const int bw  = b0 + (wid << 2);
        const int cs0 = tid >> 4, kq0 = tid & 15;
        const int cs1 = cs0 + 32;
        const int j0row = ((cs0 >> 4) << 8) + (jb << 4) + (cs0 & 15);
        const int j1row = ((cs1 >> 4) << 8) + (jb << 4) + (cs1 & 15);

        for (int s = 0; s < Tn; ++s) {
            const float* __restrict__ h_in = (s & 1) ? (dir ? hb1 : hf1) : (dir ? hb0 : hf0);
            float* __restrict__ h_out      = (s & 1) ? (dir ? hb0 : hf0) : (dir ? hb1 : hf1);
            const int t_eff = dir ? (Tn - 1 - s) : s;

            float acc[4] = {0, 0, 0, 0};
            float4 p0 = enc_wload(Wih, Whh, j0row, kq0 << 2);
            float4 p1 = enc_wload(Wih, Whh, j1row, kq0 << 2);
            *(float4*)&sg->Bs[0][cs0][kq0 << 2] = p0;
            *(float4*)&sg->Bs[0][cs1][kq0 << 2] = p1;
            __syncthreads();

            for (int kt = 0; kt < 16; ++kt) {          // K = 1024
                const int k0 = kt << 6;
                const int buf = kt & 1;
                if (kt < 15) {
                    p0 = enc_wload(Wih, Whh, j0row, k0 + 64 + (kq0 << 2));
                    p1 = enc_wload(Wih, Whh, j1row, k0 + 64 + (kq0 << 2));
                }
#pragma unroll
                for (int g = 0; g < 16; ++g) {
                    const int kk = k0 + (g << 2);
                    const float* __restrict__ abase;
                    size_t astr;
                    if (kk < En) { abase = seq + ((size_t)bw * Tn + t_eff) * En + kk; astr = (size_t)Tn * En; }
                    else         { abase = h_in + ((size_t)bw << 8) + (kk - En);      astr = HEn; }
                    float4 bf = *(const float4*)&sg->Bs[buf][c][g << 2];
#pragma unroll
                    for (int i = 0; i < 4; ++i) {
                        float4 a = *(const float4*)(abase + (size_t)i * astr);
                        acc[i] += a.x * bf.x + a.y * bf.y + a.z * bf.z + a.w * bf.w;
                    }
                }
                if (kt < 15) {
                    *(float4*)&sg->Bs[buf ^ 1][cs0][kq0 << 2] = p0;
                    *(float4*)&sg->Bs[buf ^ 1][cs1][kq0 << 2] = p1;
                }
                __syncthreads();
            }

#pragma unroll
            for (int i = 0; i < 4; ++i) sg->Gs[(wid << 2) + i][c] = acc[i];
            __syncthreads();
            {
                int row = tid >> 4, jl = tid & 15;
                int jg = (jb << 4) + jl;
                int b = b0 + row;
                float gi = sg->Gs[row][jl]      + bih[jg]           + bhh[jg];
                float gf = sg->Gs[row][16 + jl] + bih[HEn + jg]     + bhh[HEn + jg];
                float gg = sg->Gs[row][32 + jl] + bih[2 * HEn + jg] + bhh[2 * HEn + jg];
                float go = sg->Gs[row][48 + jl] + bih[3 * HEn + jg] + bhh[3 * HEn + jg];
                float ii = sigm(gi), ff = sigm(gf), tg = tanhf(gg), oo = sigm(go);
                int ci = (b << 8) + jg;
                float cn = ff * c_st[ci] + ii * tg;
                float hn = oo * tanhf(cn);
                c_st[ci] = cn;
                h_out[ci] = hn;
                enc[((size_t)t_eff * Bn + b) * Hn + dir * HEn + jg] = hn;
            }
            gsync(bar, gen);
        }
    }

    // ================= Phase 2: energT (+ init2) =================
    {
        SmemEn* se = (SmemEn*)smraw;
        const int half = tid >> 8;
        const int htid = tid & 255;
        const int tx = htid & 15, ty = htid >> 4;
        const int hslot = (bid << 1) | half;
        float (*As)[68]  = se->As[half];
        float (*Bsp)[68] = se->Bs2[half];

        for (int it = 0; it < 8; ++it) {
            const int job = hslot + (it << 9);          // 0..4095
            const int nb = job & 7, mb = job >> 3;
            const int t = mb >> 2, b0j = (mb & 3) << 6;
            float acc[4][4] = {};
            for (int kt = 0; kt < 16; ++kt) {
                int k0 = kt << 5;
#pragma unroll
                for (int r = 0; r < 8; ++r) {
                    int idx = htid + (r << 8);
                    int kk = idx & 31, row = idx >> 5;
                    As[kk][row]  = enc[((size_t)t * Bn + b0j + row) * Hn + k0 + kk];
                    Bsp[kk][row] = attn_W[(nb * 64 + row) * Hn + k0 + kk];
                }
                __syncthreads();
#pragma unroll
                for (int kk = 0; kk < 32; ++kk) {
                    float a0 = As[kk][ty * 4], a1 = As[kk][ty * 4 + 1];
                    float a2 = As[kk][ty * 4 + 2], a3 = As[kk][ty * 4 + 3];
                    float w0 = Bsp[kk][tx * 4], w1 = Bsp[kk][tx * 4 + 1];
                    float w2 = Bsp[kk][tx * 4 + 2], w3 = Bsp[kk][tx * 4 + 3];
                    acc[0][0] += a0 * w0; acc[0][1] += a0 * w1; acc[0][2] += a0 * w2; acc[0][3] += a0 * w3;
                    acc[1][0] += a1 * w0; acc[1][1] += a1 * w1; acc[1][2] += a1 * w2; acc[1][3] += a1 * w3;
                    acc[2][0] += a2 * w0; acc[2][1] += a2 * w1; acc[2][2] += a2 * w2; acc[2][3] += a2 * w3;
                    acc[3][0] += a3 * w0; acc[3][1] += a3 * w1; acc[3][2] += a3 * w2; acc[3][3] += a3 * w3;
                }
                __syncthreads();
            }
#pragma unroll
            for (int i = 0; i < 4; ++i)
#pragma unroll
                for (int q = 0; q < 4; ++q)
                    energT[((size_t)(b0j + ty * 4 + i) * Hn + nb * 64 + tx * 4 + q) * Tn + t] = acc[i][q];
        }
        __syncthreads();
        if (tid < 64) {   // init2: last_hidden gather + BOS emb, batch = bid
            int b = bid, lane = tid;
            int p1 = (nwp[b * Tn + lane] != 0);
            int p2 = (nwp[b * Tn + lane + 64] != 0);
            unsigned long long m1 = __ballot(p1), m2 = __ballot(p2);
            int cnt = __popcll(m1) + __popcll(m2);
            int idx = cnt < (Tn - 1) ? cnt : (Tn - 1);
#pragma unroll
            for (int r = 0; r < 8; ++r) {
                int j = lane + (r << 6);
                ctx0b[(b << 9) + j] = enc[((size_t)idx * Bn + b) * Hn + j];
            }
            if (lane < EMBn) embb[b * EMBn + lane] = embt[SLOTn * EMBn + lane];
        }
    }
    gsync(bar, gen);

    // ================= Phase 3: decoder (128 steps x 2 sub-phases) ========
    for (int t = 0; t < Tn; ++t) {
        const float* __restrict__ ctxin = (t & 1) ? ctx1b : ctx0b;
        float* __restrict__ ctxout      = (t & 1) ? ctx0b : ctx1b;
        const float* __restrict__ hin   = (t & 1) ? hd1 : hd0;
        float* __restrict__ hout        = (t & 1) ? hd0 : hd1;

        // ---- sub-phase A: decoder LSTM ----
        {
            SmemGemm* sg = (SmemGemm*)smraw;
            const int jb = bid & 31;
            const int b0 = (bid >> 5) << 5;
            const int c   = tid & 63;
            const int wid = tid >> 6;
            const int bw  = b0 + (wid << 2);
            const int cs0 = tid >> 4, kq0 = tid & 15;
            const int cs1 = cs0 + 32;
            const int j0row = ((cs0 >> 4) << 9) + (jb << 4) + (cs0 & 15);
            const int j1row = ((cs1 >> 4) << 9) + (jb << 4) + (cs1 & 15);

            float acc[4] = {0, 0, 0, 0};
            float4 p0 = dec_wload(Wd_ih, Wd_hh, j0row, kq0 << 2);
            float4 p1 = dec_wload(Wd_ih, Wd_hh, j1row, kq0 << 2);
            *(float4*)&sg->Bs[0][cs0][kq0 << 2] = p0;
            *(float4*)&sg->Bs[0][cs1][kq0 << 2] = p1;
            __syncthreads();

            for (int kt = 0; kt < 25; ++kt) {            // 25*64 = 1600 >= 1576
                const int k0 = kt << 6;
                const int buf = kt & 1;
                if (kt < 24) {
                    p0 = dec_wload(Wd_ih, Wd_hh, j0row, k0 + 64 + (kq0 << 2));
                    p1 = dec_wload(Wd_ih, Wd_hh, j1row, k0 + 64 + (kq0 << 2));
                }
#pragma unroll
                for (int g = 0; g < 16; ++g) {
                    const int kk = k0 + (g << 2);
                    if (kk < 1576) {
                        const float* __restrict__ abase;
                        size_t astr;
                        if (kk < 40)        { abase = embb  + (size_t)bw * EMBn + kk;                  astr = EMBn; }
                        else if (kk < 552)  { abase = ctxin + ((size_t)bw << 9) + (kk - 40);           astr = Hn; }
                        else if (kk < 1064) { abase = enc + ((size_t)t * Bn + bw) * Hn + (kk - 552);   astr = Hn; }
                        else                { abase = hin   + ((size_t)bw << 9) + (kk - 1064);         astr = Hn; }
                        float4 bf = *(const float4*)&sg->Bs[buf][c][g << 2];
#pragma unroll
                        for (int i = 0; i < 4; ++i) {
                            float4 a = *(const float4*)(abase + (size_t)i * astr);
                            acc[i] += a.x * bf.x + a.y * bf.y + a.z * bf.z + a.w * bf.w;
                        }
                    }
                }
                if (kt < 24) {
                    *(float4*)&sg->Bs[buf ^ 1][cs0][kq0 << 2] = p0;
                    *(float4*)&sg->Bs[buf ^ 1][cs1][kq0 << 2] = p1;
                }
                __syncthreads();
            }

#pragma unroll
            for (int i = 0; i < 4; ++i) sg->Gs[(wid << 2) + i][c] = acc[i];
            __syncthreads();
            {
                int row = tid >> 4, jl = tid & 15;
                int jg = ((bid & 31) << 4) + jl;
                int b = ((bid >> 5) << 5) + row;
                float gi = sg->Gs[row][jl]      + bd_ih[jg]          + bd_hh[jg];
                float gf = sg->Gs[row][16 + jl] + bd_ih[Hn + jg]     + bd_hh[Hn + jg];
                float gg = sg->Gs[row][32 + jl] + bd_ih[2 * Hn + jg] + bd_hh[2 * Hn + jg];
                float go = sg->Gs[row][48 + jl] + bd_ih[3 * Hn + jg] + bd_hh[3 * Hn + jg];
                float ii = sigm(gi), ff = sigm(gf), tg = tanhf(gg), oo = sigm(go);
                int ci = (b << 9) + jg;
                float cn = ff * cd[ci] + ii * tg;
                float hn = oo * tanhf(cn);
                cd[ci] = cn;
                hout[ci] = hn;
                if (t == 0) h0s[ci] = hn;
            }
        }
        gsync(bar, gen);

        // ---- sub-phase B: attention (lower half) + slot head (upper half), batch = bid
        {
            SmemAttn* sa = (SmemAttn*)smraw;
            const int b = bid;
            sa->hs[tid] = hout[(b << 9) + tid];
            __syncthreads();                                         // B1
            if (tid < 256) {
                const int tg = tid & 31, jg = tid >> 5;
                const float* __restrict__ ep = energT + ((size_t)b * Hn + jg * 64) * Tn + (tg << 2);
                float4 a = f4zero();
#pragma unroll 8
                for (int jj = 0; jj < 64; ++jj) {
                    float hv = sa->hs[jg * 64 + jj];
                    float4 e4 = *(const float4*)(ep + (size_t)jj * Tn);
                    a.x += e4.x * hv; a.y += e4.y * hv; a.z += e4.z * hv; a.w += e4.w * hv;
                }
                *(float4*)&sa->red2[jg][tg << 2] = a;
            } else {
                const int sl = tid & 127;
                const int kg = (tid >> 7) & 1;                       // wave-uniform
                const float* __restrict__ a0 = (kg ? ctxin : hout) + ((size_t)b << 9);
                const float* __restrict__ wb = wT4 + (size_t)kg * 128 * 128 * 4;
                float acc = 0.f;
                for (int k4 = 0; k4 < 128; ++k4) {
                    float4 w4 = *(const float4*)(wb + ((size_t)k4 * 128 + sl) * 4);
                    const float* __restrict__ ar = a0 + (k4 << 2);
                    acc += w4.x * ar[0] + w4.y * ar[1] + w4.z * ar[2] + w4.w * ar[3];
                }
                sa->pacc2[kg][sl] = acc;
            }
            __syncthreads();                                         // B2
            if (tid < 128) {
                float e = 0.f;
#pragma unroll
                for (int jg = 0; jg < 8; ++jg) e += sa->red2[jg][tid];
                bool mv = (*mflag) ? (mask_u8[(size_t)b * Tn + tid] != 0)
                                   : (mask_i32[(size_t)b * Tn + tid] != 0);
                sa->es[tid] = mv ? NEGV : e;
            } else if (tid >= 256 && tid < 384) {
                int sl = tid - 256;
                sa->sc[sl] = sa->pacc2[0][sl] + sa->pacc2[1][sl] + (sl < SLOTn ? slot_b[sl] : 0.f);
            }
            __syncthreads();                                         // B3
            if (tid < 64) {   // softmax fully in wave 0 (no block barriers)
                float v0 = sa->es[tid], v1 = sa->es[tid + 64];
                float m = fmaxf(v0, v1);
                for (int o = 32; o; o >>= 1) m = fmaxf(m, __shfl_xor(m, o));
                float q0 = __expf(v0 - m), q1 = __expf(v1 - m);
                float s = q0 + q1;
                for (int o = 32; o; o >>= 1) s += __shfl_xor(s, o);
                float inv = 1.f / s;
                sa->es[tid] = q0 * inv; sa->es[tid + 64] = q1 * inv;
            } else if (tid == 256) {  // slot log-softmax stats + argmax (first-idx ties)
                float mm = -INFINITY; int am = 0;
                for (int ss = 0; ss < SLOTn; ++ss) { float v = sa->sc[ss]; if (v > mm) { mm = v; am = ss; } }
                float sum = 0.f;
                for (int ss = 0; ss < SLOTn; ++ss) sum += __expf(sa->sc[ss] - mm);
                sa->logZ = mm + logf(sum);
                sa->amax = am;
            }
            __syncthreads();                                         // B4
            {   // ctx = sum_t' alpha * enc[t'][b][:]; 4-way t-split x 128 d-chunks
                const int th = tid >> 7;
                const int d = (tid & 127) << 2;
                const float* __restrict__ ep2 = enc + (b << 9) + d;
                const int tb = th << 5;
                float4 a = f4zero();
#pragma unroll 8
                for (int t2 = 0; t2 < 32; ++t2) {
                    float al = sa->es[tb + t2];
                    float4 e4 = *(const float4*)(ep2 + (size_t)(tb + t2) * (Bn * Hn));
                    a.x += al * e4.x; a.y += al * e4.y; a.z += al * e4.z; a.w += al * e4.w;
                }
                *(float4*)&sa->ctxp[th][d] = a;
            }
            __syncthreads();                                         // B5
            if (tid < 128) {
                int d = tid << 2;
                float4 s0 = *(float4*)&sa->ctxp[0][d];
                float4 s1 = *(float4*)&sa->ctxp[1][d];
                float4 s2 = *(float4*)&sa->ctxp[2][d];
                float4 s3 = *(float4*)&sa->ctxp[3][d];
                float4 r;
                r.x = s0.x + s1.x + s2.x + s3.x;
                r.y = s0.y + s1.y + s2.y + s3.y;
                r.z = s0.z + s1.z + s2.z + s3.z;
                r.w = s0.w + s1.w + s2.w + s3.w;
                *(float4*)(ctxout + (b << 9) + d) = r;
                if (t == 0) *(float4*)(ctx0s + (b << 9) + d) = r;
            } else if (tid >= 128 && tid < 128 + SLOTn) {
                int ss = tid - 128;
                out_slot[(size_t)b * Tn * SLOTn + t * SLOTn + ss] = sa->sc[ss] - sa->logZ;
            } else if (tid >= 256 && tid < 256 + EMBn) {
                int e2 = tid - 256;
                embb[b * EMBn + e2] = embt[sa->amax * EMBn + e2];
            }
        }
        gsync(bar, gen);
    }

    // ================= Phase 4: intent head (batch = bid) =================
    {
        SmemInt* si = (SmemInt*)smraw;
        const int n = tid & 63, kg = tid >> 6;
        const float* __restrict__ act = (kg < 4) ? (h0s + (bid << 9) + (kg << 7))
                                                 : (ctx0s + (bid << 9) + ((kg - 4) << 7));
        const float* __restrict__ wr = intent_W + n * 1024 + (kg << 7);
        float acc = 0.f;
#pragma unroll 4
        for (int kk = 0; kk < 128; ++kk) acc += wr[kk] * act[kk];
        si->pacc[kg][n] = acc;
        __syncthreads();
        if (tid < 64) {
            float s = 0.f;
#pragma unroll
            for (int kg2 = 0; kg2 < 8; ++kg2) s += si->pacc[kg2][tid];
            out_intent[bid * INTENTn + tid] = s + intent_b[tid];
        }
    }
}

// ---------------------------------------------------------------------------
extern "C" void kernel_launch(void* const* d_in, const int* in_sizes, int n_in,
                              void* d_out, int out_size, void* d_ws, size_t ws_size,
                              hipStream_t stream) {
    (void)in_sizes; (void)n_in; (void)out_size; (void)ws_size;

    const float* seq      = (const float*)d_in[0];
    const int*   nwp      = (const int*)d_in[1];
    const unsigned char* mask_u8 = (const unsigned char*)d_in[2];
    const int*   mask_i32 = (const int*)d_in[2];
    const float* embt     = (const float*)d_in[3];
    const float* Wf_ih    = (const float*)d_in[4];
    const float* Wf_hh    = (const float*)d_in[5];
    const float* bf_ih    = (const float*)d_in[6];
    const float* bf_hh    = (const float*)d_in[7];
    const float* Wb_ih    = (const float*)d_in[8];
    const float* Wb_hh    = (const float*)d_in[9];
    const float* bb_ih    = (const float*)d_in[10];
    const float* bb_hh    = (const float*)d_in[11];
    const float* Wd_ih    = (const float*)d_in[12];
    const float* Wd_hh    = (const float*)d_in[13];
    const float* bd_ih    = (const float*)d_in[14];
    const float* bd_hh    = (const float*)d_in[15];
    const float* attn_W   = (const float*)d_in[16];
    // d_in[17] = attn_b: unused (softmax shift invariance)
    const float* slot_W   = (const float*)d_in[18];
    const float* slot_b   = (const float*)d_in[19];
    const float* intent_W = (const float*)d_in[20];
    const float* intent_b = (const float*)d_in[21];

    float* Wp = (float*)d_ws;
    size_t off = 0;
    float* enc    = Wp + off; off += (size_t)Tn * Bn * Hn;   // [T,B,512]
    float* energT = Wp + off; off += (size_t)Bn * Hn * Tn;   // [B,512,T]
    float* zbase  = Wp + off;                                 // zeroed in phase 0:
    float* hf0 = Wp + off; off += Bn * HEn;
    float* hf1 = Wp + off; off += Bn * HEn;
    float* cf  = Wp + off; off += Bn * HEn;
    float* hb0 = Wp + off; off += Bn * HEn;
    float* hb1 = Wp + off; off += Bn * HEn;
    float* cb  = Wp + off; off += Bn * HEn;
    float* hd0 = Wp + off; off += Bn * Hn;
    float* hd1 = Wp + off; off += Bn * Hn;
    float* cd  = Wp + off; off += Bn * Hn;
    int nzero = (int)(Wp + off - zbase);                      // 786432 floats
    float* ctx0b = Wp + off; off += Bn * Hn;
    float* ctx1b = Wp + off; off += Bn * Hn;
    float* h0s   = Wp + off; off += Bn * Hn;
    float* ctx0s = Wp + off; off += Bn * Hn;
    float* embb  = Wp + off; off += Bn * EMBn;
    float* wT4   = Wp + off; off += 1024 * 128;               // slot_W transposed
    unsigned* barp = (unsigned*)(Wp + off); off += 8;         // bar, gen, mflag (prezeroed)
    unsigned* bar  = barp + 0;
    unsigned* gen  = barp + 1;
    int*      mflag = (int*)(barp + 2);

    float* out = (float*)d_out;
    float* out_intent = out + (size_t)Bn * Tn * SLOTn;

    prezero_k<<<1, 64, 0, stream>>>(barp);
    mega_k<<<NBLK, NTHR, 0, stream>>>(
        seq, nwp, mask_u8, mask_i32, embt,
        Wf_ih, Wf_hh, bf_ih, bf_hh, Wb_ih, Wb_hh, bb_ih, bb_hh,
        Wd_ih, Wd_hh, bd_ih, bd_hh,
        attn_W, slot_W, slot_b, intent_W, intent_b,
        enc, energT,
        hf0, hf1, cf, hb0, hb1, cb, hd0, hd1, cd,
        ctx0b, ctx1b, h0s, ctx0s, embb,
        wT4, zbase, nzero,
        bar, gen, mflag,
        out, out_intent);
}

// Round 9
// 162293.042 us; speedup vs baseline: 1.0985x; 1.0985x over previous
//
#include <hip/hip_runtime.h>
#include <math.h>

#define Bn 256
#define Tn 128
#define En 768
#define HEn 256
#define Hn 512
#define SLOTn 120
#define INTENTn 64
#define EMBn 40
#define NEGV -1e12f
#define NBLK 256
#define NTHR 512

__device__ __forceinline__ float sigm(float x) { return 1.0f / (1.0f + expf(-x)); }

__device__ __forceinline__ float4 f4zero() { float4 z; z.x = z.y = z.z = z.w = 0.f; return z; }

// ---------------------------------------------------------------------------
__global__ void prezero_k(unsigned* __restrict__ p) {
    if (threadIdx.x < 8) p[threadIdx.x] = 0u;
}

// ---------------------------------------------------------------------------
// Grid barrier, fence-minimal (R7 post-mortem: ACQUIRE-in-poll = buffer_inv/poll
// = L2 nuked continuously -> 565 GB traffic). v2: RELAXED poll (no cache op),
// RELEASE arrival (wbl2 of dirty only), ONE ACQUIRE after exit (single inv,
// bunched across blocks at barrier exit), s_dcache_inv for scalar K$.
// Co-residency: 256 blocks x 512thr, 43.5KB LDS, 64 VGPR (R7-measured) -> 1/CU.
__device__ __forceinline__ void gsync(unsigned* bar, unsigned* gen) {
    __syncthreads();   // compiler emits s_waitcnt vmcnt(0) before s_barrier
    if (threadIdx.x == 0) {
        unsigned g = __hip_atomic_load(gen, __ATOMIC_RELAXED, __HIP_MEMORY_SCOPE_AGENT);
        unsigned a = __hip_atomic_fetch_add(bar, 1u, __ATOMIC_RELEASE, __HIP_MEMORY_SCOPE_AGENT) + 1u;
        if (a == (unsigned)NBLK) {
            __hip_atomic_store(bar, 0u, __ATOMIC_RELAXED, __HIP_MEMORY_SCOPE_AGENT);
            __hip_atomic_store(gen, g + 1u, __ATOMIC_RELEASE, __HIP_MEMORY_SCOPE_AGENT);
        } else {
            while (__hip_atomic_load(gen, __ATOMIC_RELAXED, __HIP_MEMORY_SCOPE_AGENT) == g)
                __builtin_amdgcn_s_sleep(32);
        }
        (void)__hip_atomic_load(gen, __ATOMIC_ACQUIRE, __HIP_MEMORY_SCOPE_AGENT);
        __builtin_amdgcn_s_dcache_inv();
    }
    __syncthreads();
}

// ---------------------------------------------------------------------------
struct SmemGemm { float Bs[2][64][68]; float Gs[32][68]; };            // 43520 B
struct SmemEn   { float As[2][32][68]; float Bs2[2][32][68]; };        // 34816 B
struct SmemAttn { float hs[512]; float red2[8][132]; float es[128];
                  float pacc2[2][128]; float sc[128]; float ctxp[4][512];
                  float logZ; int amax; };                             // ~16.5 KB
struct SmemInt  { float pacc[8][64]; };                                // 2 KB

__device__ __forceinline__ float4 enc_wload(const float* __restrict__ Wih,
                                            const float* __restrict__ Whh,
                                            int jrow, int k) {
    return (k < En) ? *(const float4*)(Wih + (size_t)jrow * En + k)
                    : *(const float4*)(Whh + (size_t)jrow * HEn + (k - En));
}

__device__ __forceinline__ float4 dec_wload(const float* __restrict__ Wih,
                                            const float* __restrict__ Whh,
                                            int jrow, int k) {
    if (k < 1064) return *(const float4*)(Wih + (size_t)jrow * 1064 + k);
    if (k < 1576) return *(const float4*)(Whh + ((size_t)jrow << 9) + (k - 1064));
    return f4zero();
}

// ---------------------------------------------------------------------------
extern "C" __global__ __launch_bounds__(NTHR, 4) void mega_k(
    const float* __restrict__ seq, const int* __restrict__ nwp,
    const unsigned char* __restrict__ mask_u8, const int* __restrict__ mask_i32,
    const float* __restrict__ embt,
    const float* __restrict__ Wf_ih, const float* __restrict__ Wf_hh,
    const float* __restrict__ bf_ih, const float* __restrict__ bf_hh,
    const float* __restrict__ Wb_ih, const float* __restrict__ Wb_hh,
    const float* __restrict__ bb_ih, const float* __restrict__ bb_hh,
    const float* __restrict__ Wd_ih, const float* __restrict__ Wd_hh,
    const float* __restrict__ bd_ih, const float* __restrict__ bd_hh,
    const float* __restrict__ attn_W, const float* __restrict__ slot_W,
    const float* __restrict__ slot_b,
    const float* __restrict__ intent_W, const float* __restrict__ intent_b,
    float* __restrict__ enc, float* __restrict__ energT,
    float* hf0, float* hf1, float* cf, float* hb0, float* hb1, float* cb,
    float* hd0, float* hd1, float* cd,
    float* ctx0b, float* ctx1b, float* h0s, float* ctx0s, float* embb,
    float* wT4, float* zbase, int nzero,
    unsigned* bar, unsigned* gen, int* mflag,
    float* out_slot, float* out_intent)
{
    __shared__ __align__(16) char smraw[sizeof(SmemGemm)];
    const int bid = blockIdx.x;
    const int tid = threadIdx.x;

    // ================= Phase 0: init =================
    for (int i = bid * NTHR + tid; i < nzero; i += NBLK * NTHR) zbase[i] = 0.f;
    {   // slot_W transpose: exactly 131072 = NBLK*NTHR elements
        int idx = bid * NTHR + tid;
        int k = idx >> 7, s = idx & 127;
        float v = (s < SLOTn) ? slot_W[(size_t)s * 1024 + k] : 0.f;
        wT4[((size_t)(k >> 2) * 128 + s) * 4 + (k & 3)] = v;
    }
    if (bid == 0) {  // mask dtype detect (u8 vs int32); mflag prezeroed
        int found = 0;
        for (int i = tid; i < 32768; i += NTHR)
            if ((i & 3) != 0 && mask_u8[i] != 0) found = 1;
        if (found) atomicOr(mflag, 1);
    }
    gsync(bar, gen);

    // ================= Phase 1: encoder (128 steps) =================
    {
        const int dir = bid >> 7;
        const int jb  = bid & 15;
        const int b0  = ((bid >> 4) & 7) << 5;
        const float* __restrict__ Wih = dir ? Wb_ih : Wf_ih;
        const float* __restrict__ Whh = dir ? Wb_hh : Wf_hh;
        const float* __restrict__ bih = dir ? bb_ih : bf_ih;
        const float* __restrict__ bhh = dir ? bb_hh : bf_hh;
        float* __restrict__ c_st = dir ? cb : cf;
        SmemGemm* sg = (SmemGemm*)smraw;

        const int c   = tid & 63;
        const int wid = tid >> 6;
        const int bw  = b0 + (wid << 2);
        const int cs0 = tid >> 4, kq0 = tid & 15;
        const int cs1 = cs0 + 32;
        const int j0row = ((cs0 >> 4) << 8) + (jb << 4) + (cs0 & 15);
        const int j1row = ((cs1 >> 4) << 8) + (jb << 4) + (cs1 & 15);

        for (int s = 0; s < Tn; ++s) {
            const float* __restrict__ h_in = (s & 1) ? (dir ? hb1 : hf1) : (dir ? hb0 : hf0);
            float* __restrict__ h_out      = (s & 1) ? (dir ? hb0 : hf0) : (dir ? hb1 : hf1);
            const int t_eff = dir ? (Tn - 1 - s) : s;

            float acc[4] = {0, 0, 0, 0};
            float4 p0 = enc_wload(Wih, Whh, j0row, kq0 << 2);
            float4 p1 = enc_wload(Wih, Whh, j1row, kq0 << 2);
            *(float4*)&sg->Bs[0][cs0][kq0 << 2] = p0;
            *(float4*)&sg->Bs[0][cs1][kq0 << 2] = p1;
            __syncthreads();

            for (int kt = 0; kt < 16; ++kt) {          // K = 1024
                const int k0 = kt << 6;
                const int buf = kt & 1;
                if (kt < 15) {
                    p0 = enc_wload(Wih, Whh, j0row, k0 + 64 + (kq0 << 2));
                    p1 = enc_wload(Wih, Whh, j1row, k0 + 64 + (kq0 << 2));
                }
#pragma unroll
                for (int g = 0; g < 16; ++g) {
                    const int kk = k0 + (g << 2);
                    const float* __restrict__ abase;
                    size_t astr;
                    if (kk < En) { abase = seq + ((size_t)bw * Tn + t_eff) * En + kk; astr = (size_t)Tn * En; }
                    else         { abase = h_in + ((size_t)bw << 8) + (kk - En);      astr = HEn; }
                    float4 bf = *(const float4*)&sg->Bs[buf][c][g << 2];
#pragma unroll
                    for (int i = 0; i < 4; ++i) {
                        float4 a = *(const float4*)(abase + (size_t)i * astr);
                        acc[i] += a.x * bf.x + a.y * bf.y + a.z * bf.z + a.w * bf.w;
                    }
                }
                if (kt < 15) {
                    *(float4*)&sg->Bs[buf ^ 1][cs0][kq0 << 2] = p0;
                    *(float4*)&sg->Bs[buf ^ 1][cs1][kq0 << 2] = p1;
                }
                __syncthreads();
            }

#pragma unroll
            for (int i = 0; i < 4; ++i) sg->Gs[(wid << 2) + i][c] = acc[i];
            __syncthreads();
            {
                int row = tid >> 4, jl = tid & 15;
                int jg = (jb << 4) + jl;
                int b = b0 + row;
                float gi = sg->Gs[row][jl]      + bih[jg]           + bhh[jg];
                float gf = sg->Gs[row][16 + jl] + bih[HEn + jg]     + bhh[HEn + jg];
                float gg = sg->Gs[row][32 + jl] + bih[2 * HEn + jg] + bhh[2 * HEn + jg];
                float go = sg->Gs[row][48 + jl] + bih[3 * HEn + jg] + bhh[3 * HEn + jg];
                float ii = sigm(gi), ff = sigm(gf), tg = tanhf(gg), oo = sigm(go);
                int ci = (b << 8) + jg;
                float cn = ff * c_st[ci] + ii * tg;
                float hn = oo * tanhf(cn);
                c_st[ci] = cn;
                h_out[ci] = hn;
                enc[((size_t)t_eff * Bn + b) * Hn + dir * HEn + jg] = hn;
            }
            gsync(bar, gen);
        }
    }

    // ================= Phase 2: energT (+ init2) =================
    {
        SmemEn* se = (SmemEn*)smraw;
        const int half = tid >> 8;
        const int htid = tid & 255;
        const int tx = htid & 15, ty = htid >> 4;
        const int hslot = (bid << 1) | half;
        float (*As)[68]  = se->As[half];
        float (*Bsp)[68] = se->Bs2[half];

        for (int it = 0; it < 8; ++it) {
            const int job = hslot + (it << 9);          // 0..4095
            const int nb = job & 7, mb = job >> 3;
            const int t = mb >> 2, b0j = (mb & 3) << 6;
            float acc[4][4] = {};
            for (int kt = 0; kt < 16; ++kt) {
                int k0 = kt << 5;
#pragma unroll
                for (int r = 0; r < 8; ++r) {
                    int idx = htid + (r << 8);
                    int kk = idx & 31, row = idx >> 5;
                    As[kk][row]  = enc[((size_t)t * Bn + b0j + row) * Hn + k0 + kk];
                    Bsp[kk][row] = attn_W[(nb * 64 + row) * Hn + k0 + kk];
                }
                __syncthreads();
#pragma unroll
                for (int kk = 0; kk < 32; ++kk) {
                    float a0 = As[kk][ty * 4], a1 = As[kk][ty * 4 + 1];
                    float a2 = As[kk][ty * 4 + 2], a3 = As[kk][ty * 4 + 3];
                    float w0 = Bsp[kk][tx * 4], w1 = Bsp[kk][tx * 4 + 1];
                    float w2 = Bsp[kk][tx * 4 + 2], w3 = Bsp[kk][tx * 4 + 3];
                    acc[0][0] += a0 * w0; acc[0][1] += a0 * w1; acc[0][2] += a0 * w2; acc[0][3] += a0 * w3;
                    acc[1][0] += a1 * w0; acc[1][1] += a1 * w1; acc[1][2] += a1 * w2; acc[1][3] += a1 * w3;
                    acc[2][0] += a2 * w0; acc[2][1] += a2 * w1; acc[2][2] += a2 * w2; acc[2][3] += a2 * w3;
                    acc[3][0] += a3 * w0; acc[3][1] += a3 * w1; acc[3][2] += a3 * w2; acc[3][3] += a3 * w3;
                }
                __syncthreads();
            }
#pragma unroll
            for (int i = 0; i < 4; ++i)
#pragma unroll
                for (int q = 0; q < 4; ++q)
                    energT[((size_t)(b0j + ty * 4 + i) * Hn + nb * 64 + tx * 4 + q) * Tn + t] = acc[i][q];
        }
        __syncthreads();
        if (tid < 64) {   // init2: last_hidden gather + BOS emb, batch = bid
            int b = bid, lane = tid;
            int p1 = (nwp[b * Tn + lane] != 0);
            int p2 = (nwp[b * Tn + lane + 64] != 0);
            unsigned long long m1 = __ballot(p1), m2 = __ballot(p2);
            int cnt = __popcll(m1) + __popcll(m2);
            int idx = cnt < (Tn - 1) ? cnt : (Tn - 1);
#pragma unroll
            for (int r = 0; r < 8; ++r) {
                int j = lane + (r << 6);
                ctx0b[(b << 9) + j] = enc[((size_t)idx * Bn + b) * Hn + j];
            }
            if (lane < EMBn) embb[b * EMBn + lane] = embt[SLOTn * EMBn + lane];
        }
    }
    gsync(bar, gen);

    // ================= Phase 3: decoder (128 steps x 2 sub-phases) ========
    for (int t = 0; t < Tn; ++t) {
        const float* __restrict__ ctxin = (t & 1) ? ctx1b : ctx0b;
        float* __restrict__ ctxout      = (t & 1) ? ctx0b : ctx1b;
        const float* __restrict__ hin   = (t & 1) ? hd1 : hd0;
        float* __restrict__ hout        = (t & 1) ? hd0 : hd1;

        // ---- sub-phase A: decoder LSTM ----
        {
            SmemGemm* sg = (SmemGemm*)smraw;
            const int jb = bid & 31;
            const int b0 = (bid >> 5) << 5;
            const int c   = tid & 63;
            const int wid = tid >> 6;
            const int bw  = b0 + (wid << 2);
            const int cs0 = tid >> 4, kq0 = tid & 15;
            const int cs1 = cs0 + 32;
            const int j0row = ((cs0 >> 4) << 9) + (jb << 4) + (cs0 & 15);
            const int j1row = ((cs1 >> 4) << 9) + (jb << 4) + (cs1 & 15);

            float acc[4] = {0, 0, 0, 0};
            float4 p0 = dec_wload(Wd_ih, Wd_hh, j0row, kq0 << 2);
            float4 p1 = dec_wload(Wd_ih, Wd_hh, j1row, kq0 << 2);
            *(float4*)&sg->Bs[0][cs0][kq0 << 2] = p0;
            *(float4*)&sg->Bs[0][cs1][kq0 << 2] = p1;
            __syncthreads();

            for (int kt = 0; kt < 25; ++kt) {            // 25*64 = 1600 >= 1576
                const int k0 = kt << 6;
                const int buf = kt & 1;
                if (kt < 24) {
                    p0 = dec_wload(Wd_ih, Wd_hh, j0row, k0 + 64 + (kq0 << 2));
                    p1 = dec_wload(Wd_ih, Wd_hh, j1row, k0 + 64 + (kq0 << 2));
                }
#pragma unroll
                for (int g = 0; g < 16; ++g) {
                    const int kk = k0 + (g << 2);
                    if (kk < 1576) {
                        const float* __restrict__ abase;
                        size_t astr;
                        if (kk < 40)        { abase = embb  + (size_t)bw * EMBn + kk;                  astr = EMBn; }
                        else if (kk < 552)  { abase = ctxin + ((size_t)bw << 9) + (kk - 40);           astr = Hn; }
                        else if (kk < 1064) { abase = enc + ((size_t)t * Bn + bw) * Hn + (kk - 552);   astr = Hn; }
                        else                { abase = hin   + ((size_t)bw << 9) + (kk - 1064);         astr = Hn; }
                        float4 bf = *(const float4*)&sg->Bs[buf][c][g << 2];
#pragma unroll
                        for (int i = 0; i < 4; ++i) {
                            float4 a = *(const float4*)(abase + (size_t)i * astr);
                            acc[i] += a.x * bf.x + a.y * bf.y + a.z * bf.z + a.w * bf.w;
                        }
                    }
                }
                if (kt < 24) {
                    *(float4*)&sg->Bs[buf ^ 1][cs0][kq0 << 2] = p0;
                    *(float4*)&sg->Bs[buf ^ 1][cs1][kq0 << 2] = p1;
                }
                __syncthreads();
            }

#pragma unroll
            for (int i = 0; i < 4; ++i) sg->Gs[(wid << 2) + i][c] = acc[i];
            __syncthreads();
            {
                int row = tid >> 4, jl = tid & 15;
                int jg = ((bid & 31) << 4) + jl;
                int b = ((bid >> 5) << 5) + row;
                float gi = sg->Gs[row][jl]      + bd_ih[jg]          + bd_hh[jg];
                float gf = sg->Gs[row][16 + jl] + bd_ih[Hn + jg]     + bd_hh[Hn + jg];
                float gg = sg->Gs[row][32 + jl] + bd_ih[2 * Hn + jg] + bd_hh[2 * Hn + jg];
                float go = sg->Gs[row][48 + jl] + bd_ih[3 * Hn + jg] + bd_hh[3 * Hn + jg];
                float ii = sigm(gi), ff = sigm(gf), tg = tanhf(gg), oo = sigm(go);
                int ci = (b << 9) + jg;
                float cn = ff * cd[ci] + ii * tg;
                float hn = oo * tanhf(cn);
                cd[ci] = cn;
                hout[ci] = hn;
                if (t == 0) h0s[ci] = hn;
            }
        }
        gsync(bar, gen);

        // ---- sub-phase B: attention (lower half) + slot head (upper half), batch = bid
        {
            SmemAttn* sa = (SmemAttn*)smraw;
            const int b = bid;
            sa->hs[tid] = hout[(b << 9) + tid];
            __syncthreads();                                         // B1
            if (tid < 256) {
                const int tg = tid & 31, jg = tid >> 5;
                const float* __restrict__ ep = energT + ((size_t)b * Hn + jg * 64) * Tn + (tg << 2);
                float4 a = f4zero();
#pragma unroll 8
                for (int jj = 0; jj < 64; ++jj) {
                    float hv = sa->hs[jg * 64 + jj];
                    float4 e4 = *(const float4*)(ep + (size_t)jj * Tn);
                    a.x += e4.x * hv; a.y += e4.y * hv; a.z += e4.z * hv; a.w += e4.w * hv;
                }
                *(float4*)&sa->red2[jg][tg << 2] = a;
            } else {
                const int sl = tid & 127;
                const int kg = (tid >> 7) & 1;                       // wave-uniform
                const float* __restrict__ a0 = (kg ? ctxin : hout) + ((size_t)b << 9);
                const float* __restrict__ wb = wT4 + (size_t)kg * 128 * 128 * 4;
                float acc = 0.f;
                for (int k4 = 0; k4 < 128; ++k4) {
                    float4 w4 = *(const float4*)(wb + ((size_t)k4 * 128 + sl) * 4);
                    const float* __restrict__ ar = a0 + (k4 << 2);
                    acc += w4.x * ar[0] + w4.y * ar[1] + w4.z * ar[2] + w4.w * ar[3];
                }
                sa->pacc2[kg][sl] = acc;
            }
            __syncthreads();                                         // B2
            if (tid < 128) {
                float e = 0.f;
#pragma unroll
                for (int jg = 0; jg < 8; ++jg) e += sa->red2[jg][tid];
                bool mv = (*mflag) ? (mask_u8[(size_t)b * Tn + tid] != 0)
                                   : (mask_i32[(size_t)b * Tn + tid] != 0);
                sa->es[tid] = mv ? NEGV : e;
            } else if (tid >= 256 && tid < 384) {
                int sl = tid - 256;
                sa->sc[sl] = sa->pacc2[0][sl] + sa->pacc2[1][sl] + (sl < SLOTn ? slot_b[sl] : 0.f);
            }
            __syncthreads();                                         // B3
            if (tid < 64) {   // softmax fully in wave 0 (no block barriers)
                float v0 = sa->es[tid], v1 = sa->es[tid + 64];
                float m = fmaxf(v0, v1);
                for (int o = 32; o; o >>= 1) m = fmaxf(m, __shfl_xor(m, o));
                float q0 = __expf(v0 - m), q1 = __expf(v1 - m);
                float s = q0 + q1;
                for (int o = 32; o; o >>= 1) s += __shfl_xor(s, o);
                float inv = 1.f / s;
                sa->es[tid] = q0 * inv; sa->es[tid + 64] = q1 * inv;
            } else if (tid == 256) {  // slot log-softmax stats + argmax (first-idx ties)
                float mm = -INFINITY; int am = 0;
                for (int ss = 0; ss < SLOTn; ++ss) { float v = sa->sc[ss]; if (v > mm) { mm = v; am = ss; } }
                float sum = 0.f;
                for (int ss = 0; ss < SLOTn; ++ss) sum += __expf(sa->sc[ss] - mm);
                sa->logZ = mm + logf(sum);
                sa->amax = am;
            }
            __syncthreads();                                         // B4
            {   // ctx = sum_t' alpha * enc[t'][b][:]; 4-way t-split x 128 d-chunks
                const int th = tid >> 7;
                const int d = (tid & 127) << 2;
                const float* __restrict__ ep2 = enc + (b << 9) + d;
                const int tb = th << 5;
                float4 a = f4zero();
#pragma unroll 8
                for (int t2 = 0; t2 < 32; ++t2) {
                    float al = sa->es[tb + t2];
                    float4 e4 = *(const float4*)(ep2 + (size_t)(tb + t2) * (Bn * Hn));
                    a.x += al * e4.x; a.y += al * e4.y; a.z += al * e4.z; a.w += al * e4.w;
                }
                *(float4*)&sa->ctxp[th][d] = a;
            }
            __syncthreads();                                         // B5
            if (tid < 128) {
                int d = tid << 2;
                float4 s0 = *(float4*)&sa->ctxp[0][d];
                float4 s1 = *(float4*)&sa->ctxp[1][d];
                float4 s2 = *(float4*)&sa->ctxp[2][d];
                float4 s3 = *(float4*)&sa->ctxp[3][d];
                float4 r;
                r.x = s0.x + s1.x + s2.x + s3.x;
                r.y = s0.y + s1.y + s2.y + s3.y;
                r.z = s0.z + s1.z + s2.z + s3.z;
                r.w = s0.w + s1.w + s2.w + s3.w;
                *(float4*)(ctxout + (b << 9) + d) = r;
                if (t == 0) *(float4*)(ctx0s + (b << 9) + d) = r;
            } else if (tid >= 128 && tid < 128 + SLOTn) {
                int ss = tid - 128;
                out_slot[(size_t)b * Tn * SLOTn + t * SLOTn + ss] = sa->sc[ss] - sa->logZ;
            } else if (tid >= 256 && tid < 256 + EMBn) {
                int e2 = tid - 256;
                embb[b * EMBn + e2] = embt[sa->amax * EMBn + e2];
            }
        }
        gsync(bar, gen);
    }

    // ================= Phase 4: intent head (batch = bid) =================
    {
        SmemInt* si = (SmemInt*)smraw;
        const int n = tid & 63, kg = tid >> 6;
        const float* __restrict__ act = (kg < 4) ? (h0s + (bid << 9) + (kg << 7))
                                                 : (ctx0s + (bid << 9) + ((kg - 4) << 7));
        const float* __restrict__ wr = intent_W + n * 1024 + (kg << 7);
        float acc = 0.f;
#pragma unroll 4
        for (int kk = 0; kk < 128; ++kk) acc += wr[kk] * act[kk];
        si->pacc[kg][n] = acc;
        __syncthreads();
        if (tid < 64) {
            float s = 0.f;
#pragma unroll
            for (int kg2 = 0; kg2 < 8; ++kg2) s += si->pacc[kg2][tid];
            out_intent[bid * INTENTn + tid] = s + intent_b[tid];
        }
    }
}

// ---------------------------------------------------------------------------
extern "C" void kernel_launch(void* const* d_in, const int* in_sizes, int n_in,
                              void* d_out, int out_size, void* d_ws, size_t ws_size,
                              hipStream_t stream) {
    (void)in_sizes; (void)n_in; (void)out_size; (void)ws_size;

    const float* seq      = (const float*)d_in[0];
    const int*   nwp      = (const int*)d_in[1];
    const unsigned char* mask_u8 = (const unsigned char*)d_in[2];
    const int*   mask_i32 = (const int*)d_in[2];
    const float* embt     = (const float*)d_in[3];
    const float* Wf_ih    = (const float*)d_in[4];
    const float* Wf_hh    = (const float*)d_in[5];
    const float* bf_ih    = (const float*)d_in[6];
    const float* bf_hh    = (const float*)d_in[7];
    const float* Wb_ih    = (const float*)d_in[8];
    const float* Wb_hh    = (const float*)d_in[9];
    const float* bb_ih    = (const float*)d_in[10];
    const float* bb_hh    = (const float*)d_in[11];
    const float* Wd_ih    = (const float*)d_in[12];
    const float* Wd_hh    = (const float*)d_in[13];
    const float* bd_ih    = (const float*)d_in[14];
    const float* bd_hh    = (const float*)d_in[15];
    const float* attn_W   = (const float*)d_in[16];
    // d_in[17] = attn_b: unused (softmax shift invariance)
    const float* slot_W   = (const float*)d_in[18];
    const float* slot_b   = (const float*)d_in[19];
    const float* intent_W = (const float*)d_in[20];
    const float* intent_b = (const float*)d_in[21];

    float* Wp = (float*)d_ws;
    size_t off = 0;
    float* enc    = Wp + off; off += (size_t)Tn * Bn * Hn;   // [T,B,512]
    float* energT = Wp + off; off += (size_t)Bn * Hn * Tn;   // [B,512,T]
    float* zbase  = Wp + off;                                 // zeroed in phase 0:
    float* hf0 = Wp + off; off += Bn * HEn;
    float* hf1 = Wp + off; off += Bn * HEn;
    float* cf  = Wp + off; off += Bn * HEn;
    float* hb0 = Wp + off; off += Bn * HEn;
    float* hb1 = Wp + off; off += Bn * HEn;
    float* cb  = Wp + off; off += Bn * HEn;
    float* hd0 = Wp + off; off += Bn * Hn;
    float* hd1 = Wp + off; off += Bn * Hn;
    float* cd  = Wp + off; off += Bn * Hn;
    int nzero = (int)(Wp + off - zbase);                      // 786432 floats
    float* ctx0b = Wp + off; off += Bn * Hn;
    float* ctx1b = Wp + off; off += Bn * Hn;
    float* h0s   = Wp + off; off += Bn * Hn;
    float* ctx0s = Wp + off; off += Bn * Hn;
    float* embb  = Wp + off; off += Bn * EMBn;
    float* wT4   = Wp + off; off += 1024 * 128;               // slot_W transposed
    unsigned* barp = (unsigned*)(Wp + off); off += 8;         // bar, gen, mflag (prezeroed)
    unsigned* bar  = barp + 0;
    unsigned* gen  = barp + 1;
    int*      mflag = (int*)(barp + 2);

    float* out = (float*)d_out;
    float* out_intent = out + (size_t)Bn * Tn * SLOTn;

    prezero_k<<<1, 64, 0, stream>>>(barp);
    mega_k<<<NBLK, NTHR, 0, stream>>>(
        seq, nwp, mask_u8, mask_i32, embt,
        Wf_ih, Wf_hh, bf_ih, bf_hh, Wb_ih, Wb_hh, bb_ih, bb_hh,
        Wd_ih, Wd_hh, bd_ih, bd_hh,
        attn_W, slot_W, slot_b, intent_W, intent_b,
        enc, energT,
        hf0, hf1, cf, hb0, hb1, cb, hd0, hd1, cd,
        ctx0b, ctx1b, h0s, ctx0s, embb,
        wT4, zbase, nzero,
        bar, gen, mflag,
        out, out_intent);
}